// Round 2
// baseline (977.979 us; speedup 1.0000x reference)
//
#include <hip/hip_runtime.h>
#include <hip/hip_bf16.h>
#include <math.h>

// Problem constants (StackedGCN: N=100000 nodes, E=1600000 edges, 128->128->128->64)
#define NN 100000
#define EE 1600000
#define D_IN 128
#define D_H 128
#define D_OUT 64

// ---------------- utility kernels ----------------

__global__ void zero_ints(int* __restrict__ p, int n) {
    int g = blockIdx.x * 256 + threadIdx.x;
    if (g < n) p[g] = 0;
}

__global__ void hist_kernel(const int* __restrict__ dst, int* __restrict__ counts, int e) {
    int g = blockIdx.x * 256 + threadIdx.x;
    if (g < e) atomicAdd(&counts[dst[g]], 1);
}

// exclusive scan, 3-kernel version (N <= 512*256)
__global__ void scan_block(const int* __restrict__ in, int* __restrict__ out,
                           int* __restrict__ bsum, int n) {
    __shared__ int s[256];
    int t = threadIdx.x;
    int g = blockIdx.x * 256 + t;
    int v = (g < n) ? in[g] : 0;
    s[t] = v;
    for (int d = 1; d < 256; d <<= 1) {
        __syncthreads();
        int x = (t >= d) ? s[t - d] : 0;
        __syncthreads();
        s[t] += x;
    }
    if (g < n) out[g] = s[t] - v;   // exclusive within block
    if (t == 255 && bsum) bsum[blockIdx.x] = s[255];
}

__global__ void scan_sums(int* __restrict__ bsum, int nb) {
    __shared__ int s[512];
    int t = threadIdx.x;
    int v = (t < nb) ? bsum[t] : 0;
    s[t] = v;
    for (int d = 1; d < 512; d <<= 1) {
        __syncthreads();
        int x = (t >= d) ? s[t - d] : 0;
        __syncthreads();
        s[t] += x;
    }
    if (t < nb) bsum[t] = s[t] - v; // exclusive
}

__global__ void scan_add(int* __restrict__ out, const int* __restrict__ bsum, int n, int total) {
    int g = blockIdx.x * 256 + threadIdx.x;
    if (g < n) out[g] += bsum[blockIdx.x];
    if (g == 0) out[n] = total;
}

__global__ void dinv_kernel(const int* __restrict__ counts, float* __restrict__ dinv, int n) {
    int g = blockIdx.x * 256 + threadIdx.x;
    if (g < n) dinv[g] = 1.0f / sqrtf((float)(counts[g] + 1)); // +1 self-loop
}

__global__ void scatter_kernel(const int* __restrict__ src, const int* __restrict__ dst,
                               const int* __restrict__ offs, int* __restrict__ cursor,
                               int* __restrict__ csr, int e) {
    int g = blockIdx.x * 256 + threadIdx.x;
    if (g < e) {
        int d = dst[g];
        int p = offs[d] + atomicAdd(&cursor[d], 1);
        csr[p] = src[g];
    }
}

// ---------------- GEMM: Y[n x DOUT] = X[n x 128] @ W[128 x DOUT] ----------------
// 64x64 output tile per block (256 thr, 4x4 microtile). sX xor-swizzled to avoid
// the stride-128 same-bank conflict on the A reads. LDS = 32KB + 32KB = 64KB.
template <int DOUT>
__global__ __launch_bounds__(256) void gemm_x128(const float* __restrict__ X,
                                                 const float* __restrict__ W,
                                                 float* __restrict__ Y, int nrows) {
    __shared__ float sX[64][128];
    __shared__ float sW[128][64];
    const int row0 = blockIdx.x * 64;
    const int col0 = blockIdx.y * 64;
    const int tid = threadIdx.x;

    // load X tile (64 rows x 128 cols), xor-swizzled by row
    for (int i = tid; i < 64 * 32; i += 256) {
        int r = i >> 5;
        int c4 = (i & 31) << 2;
        float4 v = make_float4(0.f, 0.f, 0.f, 0.f);
        if (row0 + r < nrows) v = *(const float4*)(X + (size_t)(row0 + r) * 128 + c4);
        int m = r & 31;
        sX[r][(c4 + 0) ^ m] = v.x;
        sX[r][(c4 + 1) ^ m] = v.y;
        sX[r][(c4 + 2) ^ m] = v.z;
        sX[r][(c4 + 3) ^ m] = v.w;
    }
    // load W tile (128 x 64)
    for (int i = tid; i < 128 * 16; i += 256) {
        int k = i >> 4;
        int c4 = (i & 15) << 2;
        *(float4*)&sW[k][c4] = *(const float4*)(W + (size_t)k * DOUT + col0 + c4);
    }
    __syncthreads();

    const int tr = (tid >> 4) << 2;  // 0,4,...,60
    const int tc = (tid & 15) << 2;  // 0,4,...,60
    float acc[4][4] = {};
#pragma unroll 8
    for (int k = 0; k < 128; ++k) {
        float4 wv = *(const float4*)&sW[k][tc];
        float a0 = sX[tr + 0][k ^ ((tr + 0) & 31)];
        float a1 = sX[tr + 1][k ^ ((tr + 1) & 31)];
        float a2 = sX[tr + 2][k ^ ((tr + 2) & 31)];
        float a3 = sX[tr + 3][k ^ ((tr + 3) & 31)];
        acc[0][0] = fmaf(a0, wv.x, acc[0][0]);
        acc[0][1] = fmaf(a0, wv.y, acc[0][1]);
        acc[0][2] = fmaf(a0, wv.z, acc[0][2]);
        acc[0][3] = fmaf(a0, wv.w, acc[0][3]);
        acc[1][0] = fmaf(a1, wv.x, acc[1][0]);
        acc[1][1] = fmaf(a1, wv.y, acc[1][1]);
        acc[1][2] = fmaf(a1, wv.z, acc[1][2]);
        acc[1][3] = fmaf(a1, wv.w, acc[1][3]);
        acc[2][0] = fmaf(a2, wv.x, acc[2][0]);
        acc[2][1] = fmaf(a2, wv.y, acc[2][1]);
        acc[2][2] = fmaf(a2, wv.z, acc[2][2]);
        acc[2][3] = fmaf(a2, wv.w, acc[2][3]);
        acc[3][0] = fmaf(a3, wv.x, acc[3][0]);
        acc[3][1] = fmaf(a3, wv.y, acc[3][1]);
        acc[3][2] = fmaf(a3, wv.z, acc[3][2]);
        acc[3][3] = fmaf(a3, wv.w, acc[3][3]);
    }
#pragma unroll
    for (int i = 0; i < 4; ++i) {
        int r = row0 + tr + i;
        if (r < nrows) {
            float4 o = make_float4(acc[i][0], acc[i][1], acc[i][2], acc[i][3]);
            *(float4*)(Y + (size_t)r * DOUT + col0 + tc) = o;
        }
    }
}

// ---------------- aggregation: one wave per node ----------------
// Y[i,:] = sum_{e: dst=i} dinv[src]*dinv[i]*Xp[src,:] + dinv[i]^2*Xp[i,:] + b
template <bool RELU>
__global__ __launch_bounds__(256) void agg128(const float* __restrict__ Xp,
                                              const int* __restrict__ csr,
                                              const int* __restrict__ offs,
                                              const float* __restrict__ dinv,
                                              const float* __restrict__ bias,
                                              float* __restrict__ Y, int n) {
    int node = blockIdx.x * 4 + (threadIdx.x >> 6);
    int lane = threadIdx.x & 63;
    if (node >= n) return;
    float di = dinv[node];
    int s = offs[node], e = offs[node + 1];
    float2 acc = make_float2(0.f, 0.f);
    for (int p = s; p < e; ++p) {
        int src = csr[p];
        float c = dinv[src] * di;
        float2 v = *(const float2*)(Xp + (size_t)src * 128 + lane * 2);
        acc.x = fmaf(c, v.x, acc.x);
        acc.y = fmaf(c, v.y, acc.y);
    }
    float2 v = *(const float2*)(Xp + (size_t)node * 128 + lane * 2);
    float cs = di * di;
    acc.x = fmaf(cs, v.x, acc.x) + bias[lane * 2 + 0];
    acc.y = fmaf(cs, v.y, acc.y) + bias[lane * 2 + 1];
    if (RELU) {
        acc.x = fmaxf(acc.x, 0.f);
        acc.y = fmaxf(acc.y, 0.f);
    }
    *(float2*)(Y + (size_t)node * 128 + lane * 2) = acc;
}

// last layer: aggregation (D=64) + bias + log_softmax fused; lane = class
__global__ __launch_bounds__(256) void agg_softmax64(const float* __restrict__ Xp,
                                                     const int* __restrict__ csr,
                                                     const int* __restrict__ offs,
                                                     const float* __restrict__ dinv,
                                                     const float* __restrict__ bias,
                                                     float* __restrict__ out, int n) {
    int node = blockIdx.x * 4 + (threadIdx.x >> 6);
    int lane = threadIdx.x & 63;
    if (node >= n) return;
    float di = dinv[node];
    int s = offs[node], e = offs[node + 1];
    float acc = 0.f;
    for (int p = s; p < e; ++p) {
        int src = csr[p];
        acc = fmaf(dinv[src] * di, Xp[(size_t)src * 64 + lane], acc);
    }
    acc = fmaf(di * di, Xp[(size_t)node * 64 + lane], acc) + bias[lane];
    float m = acc;
#pragma unroll
    for (int o = 32; o > 0; o >>= 1) m = fmaxf(m, __shfl_xor(m, o, 64));
    float ex = expf(acc - m);
    float ssum = ex;
#pragma unroll
    for (int o = 32; o > 0; o >>= 1) ssum += __shfl_xor(ssum, o, 64);
    out[(size_t)node * 64 + lane] = acc - m - logf(ssum);
}

// ---------------- launcher ----------------

extern "C" void kernel_launch(void* const* d_in, const int* in_sizes, int n_in,
                              void* d_out, int out_size, void* d_ws, size_t ws_size,
                              hipStream_t stream) {
    const int* edges = (const int*)d_in[0];     // (2, E): [0..E) = src, [E..2E) = dst
    const float* feat = (const float*)d_in[1];  // (N, 128)
    const float* W0 = (const float*)d_in[2];
    const float* b0 = (const float*)d_in[3];
    const float* W1 = (const float*)d_in[4];
    const float* b1 = (const float*)d_in[5];
    const float* W2 = (const float*)d_in[6];
    const float* b2 = (const float*)d_in[7];

    const int N = NN;
    const int E = EE;
    const int NB = (N + 255) / 256;   // 391

    char* ws = (char*)d_ws;
    int* counts = (int*)ws;                    // N
    int* cursor = counts + N;                  // N (adjacent so one zero pass)
    int* offs = cursor + N;                    // N+1
    int* bsum = offs + (N + 1);                // 512
    int* csr = bsum + 512;                     // E
    float* dinv = (float*)(csr + E);           // N
    size_t off = (size_t)((char*)(dinv + N) - ws);
    off = (off + 255) & ~(size_t)255;
    float* bufA = (float*)(ws + off);          // N*128
    float* bufB = bufA + (size_t)N * 128;      // N*128

    const int* esrc = edges;
    const int* edst = edges + E;

    // CSR build + normalization
    zero_ints<<<(2 * N + 255) / 256, 256, 0, stream>>>(counts, 2 * N);
    hist_kernel<<<E / 256, 256, 0, stream>>>(edst, counts, E);
    scan_block<<<NB, 256, 0, stream>>>(counts, offs, bsum, N);
    scan_sums<<<1, 512, 0, stream>>>(bsum, NB);
    scan_add<<<NB, 256, 0, stream>>>(offs, bsum, N, E);
    dinv_kernel<<<NB, 256, 0, stream>>>(counts, dinv, N);
    scatter_kernel<<<E / 256, 256, 0, stream>>>(esrc, edst, offs, cursor, csr, E);

    dim3 g2(( N + 63) / 64, 2);
    dim3 g1(( N + 63) / 64, 1);
    int aggBlocks = (N + 3) / 4;

    // layer 0
    gemm_x128<128><<<g2, 256, 0, stream>>>(feat, W0, bufA, N);
    agg128<true><<<aggBlocks, 256, 0, stream>>>(bufA, csr, offs, dinv, b0, bufB, N);
    // layer 1
    gemm_x128<128><<<g2, 256, 0, stream>>>(bufB, W1, bufA, N);
    agg128<true><<<aggBlocks, 256, 0, stream>>>(bufA, csr, offs, dinv, b1, bufB, N);
    // layer 2 + log_softmax
    gemm_x128<64><<<g1, 256, 0, stream>>>(bufB, W2, bufA, N);
    agg_softmax64<<<aggBlocks, 256, 0, stream>>>(bufA, csr, offs, dinv, b2, (float*)d_out, N);
}

// Round 3
// 593.382 us; speedup vs baseline: 1.6481x; 1.6481x over previous
//
#include <hip/hip_runtime.h>
#include <hip/hip_bf16.h>
#include <math.h>

// StackedGCN: N=100000, E=1600000, 128 -> 128 -> 128 -> 64, fp32 in/out.
// Pipeline: activations stored bf16 (halves gather bytes), fp32 accumulation,
// MFMA bf16 GEMMs, CSR entries fused with dinv[src].
#define NN 100000
#define EE 1600000

typedef __attribute__((ext_vector_type(8))) short short8;
typedef __attribute__((ext_vector_type(4))) float f32x4;

__device__ inline unsigned short f2bf(float x) {
    unsigned u = __float_as_uint(x);
    unsigned r = u + 0x7FFFu + ((u >> 16) & 1u);
    return (unsigned short)(r >> 16);
}
__device__ inline unsigned pack2bf(float a, float b) {
    return (unsigned)f2bf(a) | ((unsigned)f2bf(b) << 16);
}
__device__ inline float bflo(unsigned u) { return __uint_as_float(u << 16); }
__device__ inline float bfhi(unsigned u) { return __uint_as_float(u & 0xFFFF0000u); }

// ---------------- CSR build ----------------

__global__ void zero_ints(int* __restrict__ p, int n) {
    int g = blockIdx.x * 256 + threadIdx.x;
    if (g < n) p[g] = 0;
}

__global__ void hist_kernel(const int* __restrict__ dst, int* __restrict__ counts, int e) {
    int g = blockIdx.x * 256 + threadIdx.x;
    if (g < e) atomicAdd(&counts[dst[g]], 1);
}

// block-level exclusive scan; also emits dinv = rsqrt(deg+1)
__global__ void scan_block(const int* __restrict__ in, int* __restrict__ out,
                           int* __restrict__ bsum, float* __restrict__ dinv, int n) {
    __shared__ int s[256];
    int t = threadIdx.x;
    int g = blockIdx.x * 256 + t;
    int v = (g < n) ? in[g] : 0;
    if (g < n) dinv[g] = 1.0f / sqrtf((float)(v + 1));  // +1 self-loop
    s[t] = v;
    for (int d = 1; d < 256; d <<= 1) {
        __syncthreads();
        int x = (t >= d) ? s[t - d] : 0;
        __syncthreads();
        s[t] += x;
    }
    if (g < n) out[g] = s[t] - v;
    if (t == 255 && bsum) bsum[blockIdx.x] = s[255];
}

__global__ void scan_sums(int* __restrict__ bsum, int nb) {
    __shared__ int s[512];
    int t = threadIdx.x;
    int v = (t < nb) ? bsum[t] : 0;
    s[t] = v;
    for (int d = 1; d < 512; d <<= 1) {
        __syncthreads();
        int x = (t >= d) ? s[t - d] : 0;
        __syncthreads();
        s[t] += x;
    }
    if (t < nb) bsum[t] = s[t] - v;
}

__global__ void scan_add(int* __restrict__ out, const int* __restrict__ bsum, int n, int total) {
    int g = blockIdx.x * 256 + threadIdx.x;
    if (g < n) out[g] += bsum[blockIdx.x];
    if (g == 0) out[n] = total;
}

// csr2[p] = (src, bits(dinv[src]))
__global__ void scatter_kernel(const int* __restrict__ src, const int* __restrict__ dst,
                               const int* __restrict__ offs, int* __restrict__ cursor,
                               const float* __restrict__ dinv, int2* __restrict__ csr2, int e) {
    int g = blockIdx.x * 256 + threadIdx.x;
    if (g < e) {
        int d = dst[g];
        int sidx = src[g];
        int p = offs[d] + atomicAdd(&cursor[d], 1);
        csr2[p] = make_int2(sidx, __float_as_int(dinv[sidx]));
    }
}

// ---------------- weight prep: fp32 row-major [K][N] -> bf16 transposed [N][K] ----------------

__global__ void prep_weights(const float* __restrict__ W0, const float* __restrict__ W1,
                             const float* __restrict__ W2, unsigned short* __restrict__ Wt0,
                             unsigned short* __restrict__ Wt1, unsigned short* __restrict__ Wt2) {
    int g = blockIdx.x * 256 + threadIdx.x;
    if (g < 16384) {                       // W0: 128x128
        int n = g >> 7, k = g & 127;
        Wt0[g] = f2bf(W0[k * 128 + n]);
    } else if (g < 32768) {                // W1: 128x128
        int i = g - 16384;
        int n = i >> 7, k = i & 127;
        Wt1[i] = f2bf(W1[k * 128 + n]);
    } else if (g < 40960) {                // W2: 128x64
        int i = g - 32768;
        int n = i >> 7, k = i & 127;       // n in [0,64)
        Wt2[i] = f2bf(W2[k * 64 + n]);
    }
}

// ---------------- MFMA GEMM: Y[bf16, nrows x DOUT] = A[nrows x 128] @ W[128 x DOUT] ----------------
// Block: 256 thr (4 waves), 128-row tile, full DOUT. Wt is bf16 [DOUT][128].
// LDS rows padded to 136 bf16 (272 B) -> 2-way bank aliasing only (free).
template <int DOUT, bool A_IS_F32>
__global__ __launch_bounds__(256) void gemm_mfma(const void* __restrict__ Aptr,
                                                 const unsigned short* __restrict__ Wt,
                                                 unsigned short* __restrict__ Y, int nrows) {
    constexpr int KP = 136;
    constexpr int NT = DOUT / 16;
    __shared__ unsigned short sA[128 * KP];
    __shared__ unsigned short sB[DOUT * KP];
    const int row0 = blockIdx.x * 128;
    const int tid = threadIdx.x;

    // stage B (bf16, contiguous k): DOUT*16 chunks of 8 bf16
    for (int i = tid; i < DOUT * 16; i += 256) {
        int n = i >> 4, c = (i & 15) * 8;
        uint4 v = *(const uint4*)(Wt + n * 128 + c);
        *(uint4*)(&sB[n * KP + c]) = v;
    }
    // stage A
    if (A_IS_F32) {
        const float* A = (const float*)Aptr;
        for (int i = tid; i < 128 * 32; i += 256) {  // float4 chunks
            int r = i >> 5, c = (i & 31) * 4;
            float4 v = make_float4(0.f, 0.f, 0.f, 0.f);
            if (row0 + r < nrows) v = *(const float4*)(A + (size_t)(row0 + r) * 128 + c);
            uint2 o;
            o.x = pack2bf(v.x, v.y);
            o.y = pack2bf(v.z, v.w);
            *(uint2*)(&sA[r * KP + c]) = o;
        }
    } else {
        const unsigned short* A = (const unsigned short*)Aptr;
        for (int i = tid; i < 128 * 16; i += 256) {  // 8-bf16 chunks
            int r = i >> 4, c = (i & 15) * 8;
            uint4 v = make_uint4(0u, 0u, 0u, 0u);
            if (row0 + r < nrows) v = *(const uint4*)(A + (size_t)(row0 + r) * 128 + c);
            *(uint4*)(&sA[r * KP + c]) = v;
        }
    }
    __syncthreads();

    const int wave = tid >> 6;
    const int lane = tid & 63;
    const int m0 = lane & 15;
    const int kq = (lane >> 4) * 8;

    f32x4 acc[2][NT];
#pragma unroll
    for (int rt = 0; rt < 2; ++rt)
#pragma unroll
        for (int t = 0; t < NT; ++t) acc[rt][t] = (f32x4){0.f, 0.f, 0.f, 0.f};

#pragma unroll
    for (int k0 = 0; k0 < 128; k0 += 32) {
        short8 a0 = *(const short8*)(&sA[(wave * 32 + m0) * KP + k0 + kq]);
        short8 a1 = *(const short8*)(&sA[(wave * 32 + 16 + m0) * KP + k0 + kq]);
#pragma unroll
        for (int t = 0; t < NT; ++t) {
            short8 b = *(const short8*)(&sB[(t * 16 + m0) * KP + k0 + kq]);
            acc[0][t] = __builtin_amdgcn_mfma_f32_16x16x32_bf16(a0, b, acc[0][t], 0, 0, 0);
            acc[1][t] = __builtin_amdgcn_mfma_f32_16x16x32_bf16(a1, b, acc[1][t], 0, 0, 0);
        }
    }

    // C/D layout: col = lane&15, row = (lane>>4)*4 + reg   [verified m89]
#pragma unroll
    for (int rt = 0; rt < 2; ++rt)
#pragma unroll
        for (int t = 0; t < NT; ++t)
#pragma unroll
            for (int r = 0; r < 4; ++r) {
                int row = row0 + wave * 32 + rt * 16 + (lane >> 4) * 4 + r;
                if (row < nrows)
                    Y[(size_t)row * DOUT + t * 16 + (lane & 15)] = f2bf(acc[rt][t][r]);
            }
}

// ---------------- aggregation D=128, bf16 in/out, 2 edges in flight per wave ----------------
__global__ __launch_bounds__(256) void agg128_bf16(const unsigned short* __restrict__ Xp,
                                                   const int2* __restrict__ csr2,
                                                   const int* __restrict__ offs,
                                                   const float* __restrict__ dinv,
                                                   const float* __restrict__ bias,
                                                   unsigned short* __restrict__ Y, int n) {
    int node = blockIdx.x * 4 + (threadIdx.x >> 6);
    if (node >= n) return;
    int lane = threadIdx.x & 63;
    int half = lane >> 5;
    int l = lane & 31;  // features 4l..4l+3
    float di = dinv[node];
    int s = offs[node], e = offs[node + 1];
    float4 acc = make_float4(0.f, 0.f, 0.f, 0.f);
    for (int p = s + half; p < e; p += 2) {
        int2 sv = csr2[p];
        float c = __int_as_float(sv.y) * di;
        uint2 u = *(const uint2*)(Xp + (size_t)sv.x * 128 + l * 4);
        acc.x = fmaf(c, bflo(u.x), acc.x);
        acc.y = fmaf(c, bfhi(u.x), acc.y);
        acc.z = fmaf(c, bflo(u.y), acc.z);
        acc.w = fmaf(c, bfhi(u.y), acc.w);
    }
    if (half == 0) {  // self-loop counted once
        uint2 u = *(const uint2*)(Xp + (size_t)node * 128 + l * 4);
        float cs = di * di;
        acc.x = fmaf(cs, bflo(u.x), acc.x);
        acc.y = fmaf(cs, bfhi(u.x), acc.y);
        acc.z = fmaf(cs, bflo(u.y), acc.z);
        acc.w = fmaf(cs, bfhi(u.y), acc.w);
    }
    acc.x += __shfl_xor(acc.x, 32);
    acc.y += __shfl_xor(acc.y, 32);
    acc.z += __shfl_xor(acc.z, 32);
    acc.w += __shfl_xor(acc.w, 32);
    if (half == 0) {
        float4 b = *(const float4*)(bias + l * 4);
        acc.x = fmaxf(acc.x + b.x, 0.f);
        acc.y = fmaxf(acc.y + b.y, 0.f);
        acc.z = fmaxf(acc.z + b.z, 0.f);
        acc.w = fmaxf(acc.w + b.w, 0.f);
        uint2 o;
        o.x = pack2bf(acc.x, acc.y);
        o.y = pack2bf(acc.z, acc.w);
        *(uint2*)(Y + (size_t)node * 128 + l * 4) = o;
    }
}

// ---------------- last layer: aggregation D=64 + bias + log_softmax, 4 edges in flight ----------------
__global__ __launch_bounds__(256) void agg_softmax64_bf16(const unsigned short* __restrict__ Xp,
                                                          const int2* __restrict__ csr2,
                                                          const int* __restrict__ offs,
                                                          const float* __restrict__ dinv,
                                                          const float* __restrict__ bias,
                                                          float* __restrict__ out, int n) {
    int node = blockIdx.x * 4 + (threadIdx.x >> 6);
    if (node >= n) return;
    int lane = threadIdx.x & 63;
    int q = lane >> 4;
    int l = lane & 15;  // features 4l..4l+3
    float di = dinv[node];
    int s = offs[node], e = offs[node + 1];
    float4 acc = make_float4(0.f, 0.f, 0.f, 0.f);
    for (int p = s + q; p < e; p += 4) {
        int2 sv = csr2[p];
        float c = __int_as_float(sv.y) * di;
        uint2 u = *(const uint2*)(Xp + (size_t)sv.x * 64 + l * 4);
        acc.x = fmaf(c, bflo(u.x), acc.x);
        acc.y = fmaf(c, bfhi(u.x), acc.y);
        acc.z = fmaf(c, bflo(u.y), acc.z);
        acc.w = fmaf(c, bfhi(u.y), acc.w);
    }
    if (q == 0) {
        uint2 u = *(const uint2*)(Xp + (size_t)node * 64 + l * 4);
        float cs = di * di;
        acc.x = fmaf(cs, bflo(u.x), acc.x);
        acc.y = fmaf(cs, bfhi(u.x), acc.y);
        acc.z = fmaf(cs, bflo(u.y), acc.z);
        acc.w = fmaf(cs, bfhi(u.y), acc.w);
    }
    // combine 4 quarter-waves
    acc.x += __shfl_xor(acc.x, 16); acc.x += __shfl_xor(acc.x, 32);
    acc.y += __shfl_xor(acc.y, 16); acc.y += __shfl_xor(acc.y, 32);
    acc.z += __shfl_xor(acc.z, 16); acc.z += __shfl_xor(acc.z, 32);
    acc.w += __shfl_xor(acc.w, 16); acc.w += __shfl_xor(acc.w, 32);
    if (q == 0) {
        float4 b = *(const float4*)(bias + l * 4);
        acc.x += b.x; acc.y += b.y; acc.z += b.z; acc.w += b.w;
        float m = fmaxf(fmaxf(acc.x, acc.y), fmaxf(acc.z, acc.w));
#pragma unroll
        for (int o = 8; o > 0; o >>= 1) m = fmaxf(m, __shfl_xor(m, o));
        float ssum = __expf(acc.x - m) + __expf(acc.y - m) + __expf(acc.z - m) + __expf(acc.w - m);
#pragma unroll
        for (int o = 8; o > 0; o >>= 1) ssum += __shfl_xor(ssum, o);
        float lg = m + __logf(ssum);
        float4 res = make_float4(acc.x - lg, acc.y - lg, acc.z - lg, acc.w - lg);
        *(float4*)(out + (size_t)node * 64 + l * 4) = res;
    }
}

// ---------------- launcher ----------------

extern "C" void kernel_launch(void* const* d_in, const int* in_sizes, int n_in,
                              void* d_out, int out_size, void* d_ws, size_t ws_size,
                              hipStream_t stream) {
    const int* edges = (const int*)d_in[0];
    const float* feat = (const float*)d_in[1];
    const float* W0 = (const float*)d_in[2];
    const float* b0 = (const float*)d_in[3];
    const float* W1 = (const float*)d_in[4];
    const float* b1 = (const float*)d_in[5];
    const float* W2 = (const float*)d_in[6];
    const float* b2 = (const float*)d_in[7];

    const int N = NN;
    const int E = EE;
    const int NB = (N + 255) / 256;  // 391

    char* ws = (char*)d_ws;
    int* counts = (int*)ws;                       // N
    int* cursor = counts + N;                     // N
    int* offs = cursor + N;                       // N+1
    int* bsum = offs + (N + 1);                   // 512
    int* pad = bsum + 512;
    size_t io = (size_t)((char*)pad - ws);
    io = (io + 7) & ~(size_t)7;
    int2* csr2 = (int2*)(ws + io);                // E pairs
    float* dinv = (float*)(csr2 + E);             // N
    unsigned short* Wt0 = (unsigned short*)(dinv + N);   // 16384
    unsigned short* Wt1 = Wt0 + 16384;                   // 16384
    unsigned short* Wt2 = Wt1 + 16384;                   // 8192
    size_t off = (size_t)((char*)(Wt2 + 8192) - ws);
    off = (off + 255) & ~(size_t)255;
    unsigned short* bufA = (unsigned short*)(ws + off);  // N*128 bf16
    unsigned short* bufB = bufA + (size_t)N * 128;       // N*128 bf16

    const int* esrc = edges;
    const int* edst = edges + E;

    // CSR build + normalization + weight prep
    zero_ints<<<(2 * N + 255) / 256, 256, 0, stream>>>(counts, 2 * N);
    prep_weights<<<160, 256, 0, stream>>>(W0, W1, W2, Wt0, Wt1, Wt2);
    hist_kernel<<<E / 256, 256, 0, stream>>>(edst, counts, E);
    scan_block<<<NB, 256, 0, stream>>>(counts, offs, bsum, dinv, N);
    scan_sums<<<1, 512, 0, stream>>>(bsum, NB);
    scan_add<<<NB, 256, 0, stream>>>(offs, bsum, N, E);
    scatter_kernel<<<E / 256, 256, 0, stream>>>(esrc, edst, offs, cursor, dinv, csr2, E);

    const int gemmBlocks = (N + 127) / 128;  // 782
    const int aggBlocks = (N + 3) / 4;       // 25000

    // layer 0
    gemm_mfma<128, true><<<gemmBlocks, 256, 0, stream>>>(feat, Wt0, bufA, N);
    agg128_bf16<<<aggBlocks, 256, 0, stream>>>(bufA, csr2, offs, dinv, b0, bufB, N);
    // layer 1
    gemm_mfma<128, false><<<gemmBlocks, 256, 0, stream>>>(bufB, Wt1, bufA, N);
    agg128_bf16<<<aggBlocks, 256, 0, stream>>>(bufA, csr2, offs, dinv, b1, bufB, N);
    // layer 2 + log_softmax
    gemm_mfma<64, false><<<gemmBlocks, 256, 0, stream>>>(bufB, Wt2, bufA, N);
    agg_softmax64_bf16<<<aggBlocks, 256, 0, stream>>>(bufA, csr2, offs, dinv, b2, (float*)d_out, N);
}

// Round 4
// 523.258 us; speedup vs baseline: 1.8690x; 1.1340x over previous
//
#include <hip/hip_runtime.h>
#include <hip/hip_bf16.h>
#include <math.h>

// StackedGCN: N=100000, E=1600000, 128 -> 128 -> 128 -> 64, fp32 in/out.
// bf16 activations (halves gather bytes), fp32 accumulation, MFMA bf16 GEMMs,
// CSR entries fused with dinv[src]. Aggregation: max-width gathers (uint4/lane),
// 4 edges in flight (D=128) / 8 edges (D=64).
#define NN 100000
#define EE 1600000

typedef __attribute__((ext_vector_type(8))) short short8;
typedef __attribute__((ext_vector_type(4))) float f32x4;

__device__ inline unsigned short f2bf(float x) {
    unsigned u = __float_as_uint(x);
    unsigned r = u + 0x7FFFu + ((u >> 16) & 1u);
    return (unsigned short)(r >> 16);
}
__device__ inline unsigned pack2bf(float a, float b) {
    return (unsigned)f2bf(a) | ((unsigned)f2bf(b) << 16);
}
__device__ inline float bflo(unsigned u) { return __uint_as_float(u << 16); }
__device__ inline float bfhi(unsigned u) { return __uint_as_float(u & 0xFFFF0000u); }

// ---------------- CSR build ----------------

__global__ void zero_ints(int* __restrict__ p, int n) {
    int g = blockIdx.x * 256 + threadIdx.x;
    if (g < n) p[g] = 0;
}

__global__ void hist_kernel(const int* __restrict__ dst, int* __restrict__ counts, int e) {
    int g = blockIdx.x * 256 + threadIdx.x;
    if (g < e) atomicAdd(&counts[dst[g]], 1);
}

// block-level exclusive scan; also emits dinv = rsqrt(deg+1)
__global__ void scan_block(const int* __restrict__ in, int* __restrict__ out,
                           int* __restrict__ bsum, float* __restrict__ dinv, int n) {
    __shared__ int s[256];
    int t = threadIdx.x;
    int g = blockIdx.x * 256 + t;
    int v = (g < n) ? in[g] : 0;
    if (g < n) dinv[g] = 1.0f / sqrtf((float)(v + 1));  // +1 self-loop
    s[t] = v;
    for (int d = 1; d < 256; d <<= 1) {
        __syncthreads();
        int x = (t >= d) ? s[t - d] : 0;
        __syncthreads();
        s[t] += x;
    }
    if (g < n) out[g] = s[t] - v;
    if (t == 255 && bsum) bsum[blockIdx.x] = s[255];
}

__global__ void scan_sums(int* __restrict__ bsum, int nb) {
    __shared__ int s[512];
    int t = threadIdx.x;
    int v = (t < nb) ? bsum[t] : 0;
    s[t] = v;
    for (int d = 1; d < 512; d <<= 1) {
        __syncthreads();
        int x = (t >= d) ? s[t - d] : 0;
        __syncthreads();
        s[t] += x;
    }
    if (t < nb) bsum[t] = s[t] - v;
}

__global__ void scan_add(int* __restrict__ out, const int* __restrict__ bsum, int n, int total) {
    int g = blockIdx.x * 256 + threadIdx.x;
    if (g < n) out[g] += bsum[blockIdx.x];
    if (g == 0) out[n] = total;
}

// csr2[p] = (src, bits(dinv[src])); cursor pre-initialized to offs (d2d copy)
__global__ void scatter_kernel(const int* __restrict__ src, const int* __restrict__ dst,
                               int* __restrict__ cursor, const float* __restrict__ dinv,
                               int2* __restrict__ csr2, int e) {
    int g = blockIdx.x * 256 + threadIdx.x;
    if (g < e) {
        int sidx = src[g];
        int p = atomicAdd(&cursor[dst[g]], 1);
        csr2[p] = make_int2(sidx, __float_as_int(dinv[sidx]));
    }
}

// ---------------- weight prep: fp32 row-major [K][N] -> bf16 transposed [N][K] ----------------

__global__ void prep_weights(const float* __restrict__ W0, const float* __restrict__ W1,
                             const float* __restrict__ W2, unsigned short* __restrict__ Wt0,
                             unsigned short* __restrict__ Wt1, unsigned short* __restrict__ Wt2) {
    int g = blockIdx.x * 256 + threadIdx.x;
    if (g < 16384) {                       // W0: 128x128
        int n = g >> 7, k = g & 127;
        Wt0[g] = f2bf(W0[k * 128 + n]);
    } else if (g < 32768) {                // W1: 128x128
        int i = g - 16384;
        int n = i >> 7, k = i & 127;
        Wt1[i] = f2bf(W1[k * 128 + n]);
    } else if (g < 40960) {                // W2: 128x64
        int i = g - 32768;
        int n = i >> 7, k = i & 127;       // n in [0,64)
        Wt2[i] = f2bf(W2[k * 64 + n]);
    }
}

// ---------------- MFMA GEMM: Y[bf16, nrows x DOUT] = A[nrows x 128] @ W[128 x DOUT] ----------------
template <int DOUT, bool A_IS_F32>
__global__ __launch_bounds__(256) void gemm_mfma(const void* __restrict__ Aptr,
                                                 const unsigned short* __restrict__ Wt,
                                                 unsigned short* __restrict__ Y, int nrows) {
    constexpr int KP = 136;
    constexpr int NT = DOUT / 16;
    __shared__ unsigned short sA[128 * KP];
    __shared__ unsigned short sB[DOUT * KP];
    const int row0 = blockIdx.x * 128;
    const int tid = threadIdx.x;

    for (int i = tid; i < DOUT * 16; i += 256) {
        int n = i >> 4, c = (i & 15) * 8;
        uint4 v = *(const uint4*)(Wt + n * 128 + c);
        *(uint4*)(&sB[n * KP + c]) = v;
    }
    if (A_IS_F32) {
        const float* A = (const float*)Aptr;
        for (int i = tid; i < 128 * 32; i += 256) {
            int r = i >> 5, c = (i & 31) * 4;
            float4 v = make_float4(0.f, 0.f, 0.f, 0.f);
            if (row0 + r < nrows) v = *(const float4*)(A + (size_t)(row0 + r) * 128 + c);
            uint2 o;
            o.x = pack2bf(v.x, v.y);
            o.y = pack2bf(v.z, v.w);
            *(uint2*)(&sA[r * KP + c]) = o;
        }
    } else {
        const unsigned short* A = (const unsigned short*)Aptr;
        for (int i = tid; i < 128 * 16; i += 256) {
            int r = i >> 4, c = (i & 15) * 8;
            uint4 v = make_uint4(0u, 0u, 0u, 0u);
            if (row0 + r < nrows) v = *(const uint4*)(A + (size_t)(row0 + r) * 128 + c);
            *(uint4*)(&sA[r * KP + c]) = v;
        }
    }
    __syncthreads();

    const int wave = tid >> 6;
    const int lane = tid & 63;
    const int m0 = lane & 15;
    const int kq = (lane >> 4) * 8;

    f32x4 acc[2][NT];
#pragma unroll
    for (int rt = 0; rt < 2; ++rt)
#pragma unroll
        for (int t = 0; t < NT; ++t) acc[rt][t] = (f32x4){0.f, 0.f, 0.f, 0.f};

#pragma unroll
    for (int k0 = 0; k0 < 128; k0 += 32) {
        short8 a0 = *(const short8*)(&sA[(wave * 32 + m0) * KP + k0 + kq]);
        short8 a1 = *(const short8*)(&sA[(wave * 32 + 16 + m0) * KP + k0 + kq]);
#pragma unroll
        for (int t = 0; t < NT; ++t) {
            short8 b = *(const short8*)(&sB[(t * 16 + m0) * KP + k0 + kq]);
            acc[0][t] = __builtin_amdgcn_mfma_f32_16x16x32_bf16(a0, b, acc[0][t], 0, 0, 0);
            acc[1][t] = __builtin_amdgcn_mfma_f32_16x16x32_bf16(a1, b, acc[1][t], 0, 0, 0);
        }
    }

    // C/D layout: col = lane&15, row = (lane>>4)*4 + reg
#pragma unroll
    for (int rt = 0; rt < 2; ++rt)
#pragma unroll
        for (int t = 0; t < NT; ++t)
#pragma unroll
            for (int r = 0; r < 4; ++r) {
                int row = row0 + wave * 32 + rt * 16 + (lane >> 4) * 4 + r;
                if (row < nrows)
                    Y[(size_t)row * DOUT + t * 16 + (lane & 15)] = f2bf(acc[rt][t][r]);
            }
}

// ---------------- aggregation D=128: quarter-wave per edge, uint4 gathers ----------------
// 4 edges in flight per node; lane l of a quarter covers features 8l..8l+7.
__global__ __launch_bounds__(256) void agg128_bf16(const unsigned short* __restrict__ Xp,
                                                   const int2* __restrict__ csr2,
                                                   const int* __restrict__ offs,
                                                   const float* __restrict__ dinv,
                                                   const float* __restrict__ bias,
                                                   unsigned short* __restrict__ Y, int n) {
    int node = blockIdx.x * 4 + (threadIdx.x >> 6);
    if (node >= n) return;
    int lane = threadIdx.x & 63;
    int q = lane >> 4;   // quarter 0..3
    int l = lane & 15;   // features 8l..8l+7
    float di = dinv[node];
    int s = offs[node], e = offs[node + 1];
    float a0 = 0.f, a1 = 0.f, a2 = 0.f, a3 = 0.f, a4 = 0.f, a5 = 0.f, a6 = 0.f, a7 = 0.f;
    for (int p = s + q; p < e; p += 4) {
        int2 sv = csr2[p];
        float c = __int_as_float(sv.y) * di;
        uint4 u = *(const uint4*)(Xp + (size_t)sv.x * 128 + l * 8);
        a0 = fmaf(c, bflo(u.x), a0); a1 = fmaf(c, bfhi(u.x), a1);
        a2 = fmaf(c, bflo(u.y), a2); a3 = fmaf(c, bfhi(u.y), a3);
        a4 = fmaf(c, bflo(u.z), a4); a5 = fmaf(c, bfhi(u.z), a5);
        a6 = fmaf(c, bflo(u.w), a6); a7 = fmaf(c, bfhi(u.w), a7);
    }
    if (q == 0) {  // self-loop counted once
        float cs = di * di;
        uint4 u = *(const uint4*)(Xp + (size_t)node * 128 + l * 8);
        a0 = fmaf(cs, bflo(u.x), a0); a1 = fmaf(cs, bfhi(u.x), a1);
        a2 = fmaf(cs, bflo(u.y), a2); a3 = fmaf(cs, bfhi(u.y), a3);
        a4 = fmaf(cs, bflo(u.z), a4); a5 = fmaf(cs, bfhi(u.z), a5);
        a6 = fmaf(cs, bflo(u.w), a6); a7 = fmaf(cs, bfhi(u.w), a7);
    }
    // reduce across quarters (xor 16, 32)
    a0 += __shfl_xor(a0, 16); a0 += __shfl_xor(a0, 32);
    a1 += __shfl_xor(a1, 16); a1 += __shfl_xor(a1, 32);
    a2 += __shfl_xor(a2, 16); a2 += __shfl_xor(a2, 32);
    a3 += __shfl_xor(a3, 16); a3 += __shfl_xor(a3, 32);
    a4 += __shfl_xor(a4, 16); a4 += __shfl_xor(a4, 32);
    a5 += __shfl_xor(a5, 16); a5 += __shfl_xor(a5, 32);
    a6 += __shfl_xor(a6, 16); a6 += __shfl_xor(a6, 32);
    a7 += __shfl_xor(a7, 16); a7 += __shfl_xor(a7, 32);
    if (q == 0) {
        float4 bA = *(const float4*)(bias + l * 8);
        float4 bB = *(const float4*)(bias + l * 8 + 4);
        a0 = fmaxf(a0 + bA.x, 0.f); a1 = fmaxf(a1 + bA.y, 0.f);
        a2 = fmaxf(a2 + bA.z, 0.f); a3 = fmaxf(a3 + bA.w, 0.f);
        a4 = fmaxf(a4 + bB.x, 0.f); a5 = fmaxf(a5 + bB.y, 0.f);
        a6 = fmaxf(a6 + bB.z, 0.f); a7 = fmaxf(a7 + bB.w, 0.f);
        uint4 o;
        o.x = pack2bf(a0, a1); o.y = pack2bf(a2, a3);
        o.z = pack2bf(a4, a5); o.w = pack2bf(a6, a7);
        *(uint4*)(Y + (size_t)node * 128 + l * 8) = o;
    }
}

// ---------------- last layer D=64: eighth-wave per edge (8 in flight) + log_softmax ----------------
__global__ __launch_bounds__(256) void agg_softmax64_bf16(const unsigned short* __restrict__ Xp,
                                                          const int2* __restrict__ csr2,
                                                          const int* __restrict__ offs,
                                                          const float* __restrict__ dinv,
                                                          const float* __restrict__ bias,
                                                          float* __restrict__ out, int n) {
    int node = blockIdx.x * 4 + (threadIdx.x >> 6);
    if (node >= n) return;
    int lane = threadIdx.x & 63;
    int g8 = lane >> 3;  // eighth 0..7
    int l = lane & 7;    // features 8l..8l+7
    float di = dinv[node];
    int s = offs[node], e = offs[node + 1];
    float a0 = 0.f, a1 = 0.f, a2 = 0.f, a3 = 0.f, a4 = 0.f, a5 = 0.f, a6 = 0.f, a7 = 0.f;
    for (int p = s + g8; p < e; p += 8) {
        int2 sv = csr2[p];
        float c = __int_as_float(sv.y) * di;
        uint4 u = *(const uint4*)(Xp + (size_t)sv.x * 64 + l * 8);
        a0 = fmaf(c, bflo(u.x), a0); a1 = fmaf(c, bfhi(u.x), a1);
        a2 = fmaf(c, bflo(u.y), a2); a3 = fmaf(c, bfhi(u.y), a3);
        a4 = fmaf(c, bflo(u.z), a4); a5 = fmaf(c, bfhi(u.z), a5);
        a6 = fmaf(c, bflo(u.w), a6); a7 = fmaf(c, bfhi(u.w), a7);
    }
    if (g8 == 0) {
        float cs = di * di;
        uint4 u = *(const uint4*)(Xp + (size_t)node * 64 + l * 8);
        a0 = fmaf(cs, bflo(u.x), a0); a1 = fmaf(cs, bfhi(u.x), a1);
        a2 = fmaf(cs, bflo(u.y), a2); a3 = fmaf(cs, bfhi(u.y), a3);
        a4 = fmaf(cs, bflo(u.z), a4); a5 = fmaf(cs, bfhi(u.z), a5);
        a6 = fmaf(cs, bflo(u.w), a6); a7 = fmaf(cs, bfhi(u.w), a7);
    }
    // reduce across eighths (xor 8, 16, 32)
    a0 += __shfl_xor(a0, 8); a0 += __shfl_xor(a0, 16); a0 += __shfl_xor(a0, 32);
    a1 += __shfl_xor(a1, 8); a1 += __shfl_xor(a1, 16); a1 += __shfl_xor(a1, 32);
    a2 += __shfl_xor(a2, 8); a2 += __shfl_xor(a2, 16); a2 += __shfl_xor(a2, 32);
    a3 += __shfl_xor(a3, 8); a3 += __shfl_xor(a3, 16); a3 += __shfl_xor(a3, 32);
    a4 += __shfl_xor(a4, 8); a4 += __shfl_xor(a4, 16); a4 += __shfl_xor(a4, 32);
    a5 += __shfl_xor(a5, 8); a5 += __shfl_xor(a5, 16); a5 += __shfl_xor(a5, 32);
    a6 += __shfl_xor(a6, 8); a6 += __shfl_xor(a6, 16); a6 += __shfl_xor(a6, 32);
    a7 += __shfl_xor(a7, 8); a7 += __shfl_xor(a7, 16); a7 += __shfl_xor(a7, 32);
    if (g8 == 0) {
        float4 bA = *(const float4*)(bias + l * 8);
        float4 bB = *(const float4*)(bias + l * 8 + 4);
        a0 += bA.x; a1 += bA.y; a2 += bA.z; a3 += bA.w;
        a4 += bB.x; a5 += bB.y; a6 += bB.z; a7 += bB.w;
        float m = fmaxf(fmaxf(fmaxf(a0, a1), fmaxf(a2, a3)), fmaxf(fmaxf(a4, a5), fmaxf(a6, a7)));
#pragma unroll
        for (int o = 4; o > 0; o >>= 1) m = fmaxf(m, __shfl_xor(m, o));
        float ssum = __expf(a0 - m) + __expf(a1 - m) + __expf(a2 - m) + __expf(a3 - m) +
                     __expf(a4 - m) + __expf(a5 - m) + __expf(a6 - m) + __expf(a7 - m);
#pragma unroll
        for (int o = 4; o > 0; o >>= 1) ssum += __shfl_xor(ssum, o);
        float lg = m + __logf(ssum);
        float4 r0 = make_float4(a0 - lg, a1 - lg, a2 - lg, a3 - lg);
        float4 r1 = make_float4(a4 - lg, a5 - lg, a6 - lg, a7 - lg);
        *(float4*)(out + (size_t)node * 64 + l * 8) = r0;
        *(float4*)(out + (size_t)node * 64 + l * 8 + 4) = r1;
    }
}

// ---------------- launcher ----------------

extern "C" void kernel_launch(void* const* d_in, const int* in_sizes, int n_in,
                              void* d_out, int out_size, void* d_ws, size_t ws_size,
                              hipStream_t stream) {
    const int* edges = (const int*)d_in[0];
    const float* feat = (const float*)d_in[1];
    const float* W0 = (const float*)d_in[2];
    const float* b0 = (const float*)d_in[3];
    const float* W1 = (const float*)d_in[4];
    const float* b1 = (const float*)d_in[5];
    const float* W2 = (const float*)d_in[6];
    const float* b2 = (const float*)d_in[7];

    const int N = NN;
    const int E = EE;
    const int NB = (N + 255) / 256;  // 391

    char* ws = (char*)d_ws;
    int* counts = (int*)ws;                       // N
    int* cursor = counts + N;                     // N
    int* offs = cursor + N;                       // N+1
    int* bsum = offs + (N + 1);                   // 512
    int* pad = bsum + 512;
    size_t io = (size_t)((char*)pad - ws);
    io = (io + 7) & ~(size_t)7;
    int2* csr2 = (int2*)(ws + io);                // E pairs
    float* dinv = (float*)(csr2 + E);             // N
    unsigned short* Wt0 = (unsigned short*)(dinv + N);   // 16384
    unsigned short* Wt1 = Wt0 + 16384;                   // 16384
    unsigned short* Wt2 = Wt1 + 16384;                   // 8192
    size_t off = (size_t)((char*)(Wt2 + 8192) - ws);
    off = (off + 255) & ~(size_t)255;
    unsigned short* bufA = (unsigned short*)(ws + off);  // N*128 bf16
    unsigned short* bufB = bufA + (size_t)N * 128;       // N*128 bf16

    const int* esrc = edges;
    const int* edst = edges + E;

    // CSR build + normalization + weight prep
    zero_ints<<<NB, 256, 0, stream>>>(counts, N);
    prep_weights<<<160, 256, 0, stream>>>(W0, W1, W2, Wt0, Wt1, Wt2);
    hist_kernel<<<E / 256, 256, 0, stream>>>(edst, counts, E);
    scan_block<<<NB, 256, 0, stream>>>(counts, offs, bsum, dinv, N);
    scan_sums<<<1, 512, 0, stream>>>(bsum, NB);
    scan_add<<<NB, 256, 0, stream>>>(offs, bsum, N, E);
    hipMemcpyAsync(cursor, offs, (size_t)N * sizeof(int), hipMemcpyDeviceToDevice, stream);
    scatter_kernel<<<E / 256, 256, 0, stream>>>(esrc, edst, cursor, dinv, csr2, E);

    const int gemmBlocks = (N + 127) / 128;  // 782
    const int aggBlocks = (N + 3) / 4;       // 25000

    // layer 0
    gemm_mfma<128, true><<<gemmBlocks, 256, 0, stream>>>(feat, Wt0, bufA, N);
    agg128_bf16<<<aggBlocks, 256, 0, stream>>>(bufA, csr2, offs, dinv, b0, bufB, N);
    // layer 1
    gemm_mfma<128, false><<<gemmBlocks, 256, 0, stream>>>(bufB, Wt1, bufA, N);
    agg128_bf16<<<aggBlocks, 256, 0, stream>>>(bufA, csr2, offs, dinv, b1, bufB, N);
    // layer 2 + log_softmax
    gemm_mfma<64, false><<<gemmBlocks, 256, 0, stream>>>(bufB, Wt2, bufA, N);
    agg_softmax64_bf16<<<aggBlocks, 256, 0, stream>>>(bufA, csr2, offs, dinv, b2, (float*)d_out, N);
}